// Round 1
// baseline (135.925 us; speedup 1.0000x reference)
//
#include <hip/hip_runtime.h>
#include <hip/hip_fp16.h>

typedef _Float16 f16x8 __attribute__((ext_vector_type(8)));
typedef float f32x4 __attribute__((ext_vector_type(4)));

#define FEAT 44
#define TED  84
#define ESTR 88      // padded embedh row stride in halves (176 B, 16B-aligned)
#define MT   256     // nodes per block

// ---------------- kernel 1: weight repack fp32 -> fp16 ----------------
__global__ void prep_weights(const float* __restrict__ w0, const float* __restrict__ w1,
                             const float* __restrict__ w2,
                             _Float16* __restrict__ w0h, _Float16* __restrict__ w1h,
                             _Float16* __restrict__ w2h) {
    int t = threadIdx.x;
    for (int i = t; i < 64 * 128; i += 256) w0h[i] = (_Float16)w0[i];
    for (int i = t; i < 32 * 64;  i += 256) w1h[i] = (_Float16)w1[i];
    // w2 is [4][32]; pad to [16][32] with zeros so the MFMA B-fragment reads zeros
    for (int i = t; i < 16 * 32;  i += 256) w2h[i] = (i < 4 * 32) ? (_Float16)w2[i] : (_Float16)0.f;
}

// ---------------- kernel 2: per-graph embed + inv_std ----------------
__global__ void embed_kernel(const float* __restrict__ t_arr, const float* __restrict__ W_f,
                             const float* __restrict__ embed_w, const float* __restrict__ embed_b,
                             _Float16* __restrict__ embedh, float* __restrict__ inv_std) {
    __shared__ float temb[TED];
    int g   = blockIdx.x;
    int tid = threadIdx.x;
    float tv = t_arr[g];
    if (tid < TED) {
        int j   = (tid < TED / 2) ? tid : tid - TED / 2;
        float x = tv * W_f[j] * 6.283185307179586f;
        temb[tid] = (tid < TED / 2) ? sinf(x) : cosf(x);
    }
    __syncthreads();
    if (tid < TED) {
        const float* wr = embed_w + tid * TED;   // [out][in], row-major
        float s = embed_b[tid];
        #pragma unroll 4
        for (int j = 0; j < TED; ++j) s = fmaf(temb[j], wr[j], s);
        float sw = s / (1.0f + __expf(-s));      // swish
        embedh[(size_t)g * ESTR + tid] = (_Float16)sw;
    } else if (tid < ESTR) {
        embedh[(size_t)g * ESTR + tid] = (_Float16)0.f;  // pad
    } else if (tid == ESTR) {
        const float c = 6.437751649736401f;      // 2*ln(25)
        inv_std[g] = rsqrtf(expm1f(c * tv) / c);
    }
}

// ---------------- kernel 3: main fused MLP ----------------
// LDS map (byte offsets), regions reused across phases:
//   A0 [0,65536):      [256][128] f16, row stride 256B, swz ^((row&7)<<4)
//   A1 [0,32768):      [256][ 64] f16, row stride 128B, swz ^((row&7)<<4)
//   A2 [32768,49152):  [256][ 32] f16, row stride  64B, swz ^((row&3)<<4)
//   O  [65536,69632):  [256][4] f32 output staging
//   istd [69632,70656): [256] f32
#define A2_OFF   32768
#define O_OFF    65536
#define ISTD_OFF 69632

__device__ __forceinline__ float swishf(float x) {
    return x / (1.0f + __expf(-x));
}

__global__ __launch_bounds__(256, 2)
void scorenet_main(const float* __restrict__ node_attr,
                   const int* __restrict__ gptr, int B,
                   const _Float16* __restrict__ embedh,
                   const float* __restrict__ inv_std_g,
                   const _Float16* __restrict__ w0h,
                   const _Float16* __restrict__ w1h,
                   const _Float16* __restrict__ w2h,
                   const float* __restrict__ b0,
                   const float* __restrict__ b1,
                   const float* __restrict__ b2,
                   float* __restrict__ out) {
    __shared__ __align__(16) char lds[70656];

    const int t    = threadIdx.x;
    const int n0   = blockIdx.x * MT;
    const int lane = t & 63;
    const int wid  = t >> 6;
    const int lr   = lane & 15;   // fragment row (A) / col (B,C)
    const int lk   = lane >> 4;   // k-group (A/B), row-group (C)

    // ---- assembly: row t = seg lookup + embed copy; linear node_attr load ----
    {
        int node = n0 + t;
        int lo = 0, hi = B + 1;                 // upper_bound(ptr, node) - 1
        while (lo < hi) { int mid = (lo + hi) >> 1; if (gptr[mid] <= node) lo = mid + 1; else hi = mid; }
        int seg = lo - 1;
        ((float*)(lds + ISTD_OFF))[t] = inv_std_g[seg];
        const uint2* src = (const uint2*)(embedh + (size_t)seg * ESTR);
        const int rswz = (t & 7) << 4;
        #pragma unroll
        for (int m = 0; m < 21; ++m) {          // 84 halves = 21 x 8B, 8B-aligned (88+8m)
            uint2 v = src[m];
            int addr = t * 256 + 88 + m * 8;
            *(uint2*)(lds + (addr ^ rswz)) = v;
        }
    }
    {
        // 256 rows x 44 floats = 2816 float4, 11 per thread, fully coalesced
        const float4* src = (const float4*)(node_attr + (size_t)n0 * FEAT);
        #pragma unroll
        for (int i = 0; i < 11; ++i) {
            int f4   = i * 256 + t;
            int row  = (int)(((unsigned)f4 * 381301u) >> 22);  // f4 / 11
            int colq = f4 - row * 11;
            float4 v = src[f4];
            union { _Float16 h[4]; uint2 u; } cv;
            cv.h[0] = (_Float16)v.x; cv.h[1] = (_Float16)v.y;
            cv.h[2] = (_Float16)v.z; cv.h[3] = (_Float16)v.w;
            int addr = row * 256 + colq * 8;
            *(uint2*)(lds + (addr ^ ((row & 7) << 4))) = cv.u;
        }
    }
    __syncthreads();

    const int rbase = wid * 64;

    // ---- layer 0: [256x128] x [128x64] ----
    f16x8 bw0[4][4];
    #pragma unroll
    for (int kt = 0; kt < 4; ++kt)
        #pragma unroll
        for (int ct = 0; ct < 4; ++ct)
            bw0[kt][ct] = *(const f16x8*)(w0h + (ct * 16 + lr) * 128 + kt * 32 + lk * 8);

    f32x4 acc0[4][4] = {};
    #pragma unroll
    for (int kt = 0; kt < 4; ++kt) {
        f16x8 a[4];
        #pragma unroll
        for (int rt = 0; rt < 4; ++rt) {
            int row  = rbase + rt * 16 + lr;
            int addr = row * 256 + kt * 64 + lk * 16;
            a[rt] = *(const f16x8*)(lds + (addr ^ ((row & 7) << 4)));
        }
        #pragma unroll
        for (int rt = 0; rt < 4; ++rt)
            #pragma unroll
            for (int ct = 0; ct < 4; ++ct)
                acc0[rt][ct] = __builtin_amdgcn_mfma_f32_16x16x32_f16(a[rt], bw0[kt][ct], acc0[rt][ct], 0, 0, 0);
    }
    __syncthreads();   // everyone done reading A0 before overwriting with A1

    {
        float bias0[4];
        #pragma unroll
        for (int ct = 0; ct < 4; ++ct) bias0[ct] = b0[ct * 16 + lr];
        #pragma unroll
        for (int rt = 0; rt < 4; ++rt)
            #pragma unroll
            for (int ct = 0; ct < 4; ++ct)
                #pragma unroll
                for (int r = 0; r < 4; ++r) {
                    float sw = swishf(acc0[rt][ct][r] + bias0[ct]);
                    int row  = rbase + rt * 16 + lk * 4 + r;
                    int col  = ct * 16 + lr;
                    int addr = row * 128 + col * 2;
                    *(_Float16*)(lds + (addr ^ ((row & 7) << 4))) = (_Float16)sw;
                }
    }
    __syncthreads();

    // ---- layer 1: [256x64] x [64x32] ----
    f16x8 bw1[2][2];
    #pragma unroll
    for (int kt = 0; kt < 2; ++kt)
        #pragma unroll
        for (int ct = 0; ct < 2; ++ct)
            bw1[kt][ct] = *(const f16x8*)(w1h + (ct * 16 + lr) * 64 + kt * 32 + lk * 8);

    f32x4 acc1[4][2] = {};
    #pragma unroll
    for (int kt = 0; kt < 2; ++kt) {
        f16x8 a[4];
        #pragma unroll
        for (int rt = 0; rt < 4; ++rt) {
            int row  = rbase + rt * 16 + lr;
            int addr = row * 128 + kt * 64 + lk * 16;
            a[rt] = *(const f16x8*)(lds + (addr ^ ((row & 7) << 4)));
        }
        #pragma unroll
        for (int rt = 0; rt < 4; ++rt)
            #pragma unroll
            for (int ct = 0; ct < 2; ++ct)
                acc1[rt][ct] = __builtin_amdgcn_mfma_f32_16x16x32_f16(a[rt], bw1[kt][ct], acc1[rt][ct], 0, 0, 0);
    }
    // A2 region disjoint from A1 -> no barrier needed before writes
    {
        float bias1[2];
        #pragma unroll
        for (int ct = 0; ct < 2; ++ct) bias1[ct] = b1[ct * 16 + lr];
        #pragma unroll
        for (int rt = 0; rt < 4; ++rt)
            #pragma unroll
            for (int ct = 0; ct < 2; ++ct)
                #pragma unroll
                for (int r = 0; r < 4; ++r) {
                    float sw = swishf(acc1[rt][ct][r] + bias1[ct]);
                    int row  = rbase + rt * 16 + lk * 4 + r;
                    int col  = ct * 16 + lr;
                    int addr = A2_OFF + row * 64 + col * 2;
                    *(_Float16*)(lds + (addr ^ ((row & 3) << 4))) = (_Float16)sw;
                }
    }
    __syncthreads();

    // ---- layer 2: [256x32] x [32x16(4 valid)] ----
    f16x8 bw2 = *(const f16x8*)(w2h + lr * 32 + lk * 8);
    f32x4 acc2[4] = {};
    #pragma unroll
    for (int rt = 0; rt < 4; ++rt) {
        int row  = rbase + rt * 16 + lr;
        int addr = A2_OFF + row * 64 + lk * 16;
        f16x8 a  = *(const f16x8*)(lds + (addr ^ ((row & 3) << 4)));
        acc2[rt] = __builtin_amdgcn_mfma_f32_16x16x32_f16(a, bw2, acc2[rt], 0, 0, 0);
    }
    {
        float bias2 = (lr < 4) ? b2[lr] : 0.f;
        float* O = (float*)(lds + O_OFF);
        const float* istd = (const float*)(lds + ISTD_OFF);
        #pragma unroll
        for (int rt = 0; rt < 4; ++rt)
            #pragma unroll
            for (int r = 0; r < 4; ++r) {
                float sw = swishf(acc2[rt][r] + bias2);
                int row  = rbase + rt * 16 + lk * 4 + r;
                if (lr < 4) O[row * 4 + lr] = sw * istd[row];
            }
    }
    __syncthreads();

    float4 o = ((const float4*)(lds + O_OFF))[t];
    ((float4*)(out + (size_t)n0 * 4))[t] = o;
}

// ---------------- launch ----------------
extern "C" void kernel_launch(void* const* d_in, const int* in_sizes, int n_in,
                              void* d_out, int out_size, void* d_ws, size_t ws_size,
                              hipStream_t stream) {
    const float* node_attr = (const float*)d_in[0];
    const float* t_arr     = (const float*)d_in[1];
    const int*   gptr      = (const int*)d_in[2];
    const float* W_f       = (const float*)d_in[3];
    const float* embed_w   = (const float*)d_in[4];
    const float* embed_b   = (const float*)d_in[5];
    const float* w0        = (const float*)d_in[6];
    const float* b0        = (const float*)d_in[7];
    const float* w1        = (const float*)d_in[8];
    const float* b1        = (const float*)d_in[9];
    const float* w2        = (const float*)d_in[10];
    const float* b2        = (const float*)d_in[11];
    float* out = (float*)d_out;

    const int N = in_sizes[0] / FEAT;
    const int B = in_sizes[1];

    char* ws = (char*)d_ws;
    size_t off = 0;
    _Float16* embedh = (_Float16*)(ws + off); off += (size_t)B * ESTR * sizeof(_Float16); // 720896
    off = (off + 1023) & ~(size_t)1023;
    float*    inv_std = (float*)(ws + off);   off += (size_t)B * sizeof(float);
    off = (off + 1023) & ~(size_t)1023;
    _Float16* w0h = (_Float16*)(ws + off);    off += 64 * 128 * sizeof(_Float16);
    _Float16* w1h = (_Float16*)(ws + off);    off += 32 * 64 * sizeof(_Float16);
    _Float16* w2h = (_Float16*)(ws + off);    off += 16 * 32 * sizeof(_Float16);

    prep_weights<<<1, 256, 0, stream>>>(w0, w1, w2, w0h, w1h, w2h);
    embed_kernel<<<B, 128, 0, stream>>>(t_arr, W_f, embed_w, embed_b, embedh, inv_std);
    scorenet_main<<<N / MT, 256, 0, stream>>>(node_attr, gptr, B, embedh, inv_std,
                                              w0h, w1h, w2h, b0, b1, b2, out);
}

// Round 2
// 121.410 us; speedup vs baseline: 1.1196x; 1.1196x over previous
//
#include <hip/hip_runtime.h>
#include <hip/hip_fp16.h>

typedef _Float16 f16x8 __attribute__((ext_vector_type(8)));
typedef float f32x4 __attribute__((ext_vector_type(4)));

#define FEAT 44
#define TED  84
#define ESTR 88      // padded embedh row stride in halves (176 B)
#define MT   256     // nodes per block
#define ISTD_OFF 65536

// ---------------- kernel 1: weight repack fp32 -> fp16 ----------------
__global__ void prep_weights(const float* __restrict__ w0, const float* __restrict__ w1,
                             const float* __restrict__ w2,
                             _Float16* __restrict__ w0h, _Float16* __restrict__ w1h,
                             _Float16* __restrict__ w2h) {
    int t = threadIdx.x;
    for (int i = t; i < 64 * 128; i += 256) w0h[i] = (_Float16)w0[i];
    for (int i = t; i < 32 * 64;  i += 256) w1h[i] = (_Float16)w1[i];
    for (int i = t; i < 16 * 32;  i += 256) w2h[i] = (i < 4 * 32) ? (_Float16)w2[i] : (_Float16)0.f;
}

// ---------------- kernel 2: per-graph embed + inv_std ----------------
__global__ void embed_kernel(const float* __restrict__ t_arr, const float* __restrict__ W_f,
                             const float* __restrict__ embed_w, const float* __restrict__ embed_b,
                             _Float16* __restrict__ embedh, float* __restrict__ inv_std) {
    __shared__ float temb[TED];
    int g   = blockIdx.x;
    int tid = threadIdx.x;
    float tv = t_arr[g];
    if (tid < TED) {
        int j   = (tid < TED / 2) ? tid : tid - TED / 2;
        float x = tv * W_f[j] * 6.283185307179586f;
        temb[tid] = (tid < TED / 2) ? sinf(x) : cosf(x);
    }
    __syncthreads();
    if (tid < TED) {
        const float* wr = embed_w + tid * TED;
        float s = embed_b[tid];
        #pragma unroll 4
        for (int j = 0; j < TED; ++j) s = fmaf(temb[j], wr[j], s);
        float sw = s / (1.0f + __expf(-s));
        embedh[(size_t)g * ESTR + tid] = (_Float16)sw;
    } else if (tid < ESTR) {
        embedh[(size_t)g * ESTR + tid] = (_Float16)0.f;
    } else if (tid == ESTR) {
        const float c = 6.437751649736401f;      // 2*ln(25)
        inv_std[g] = rsqrtf(expm1f(c * tv) / c);
    }
}

// ---------------- kernel 3: main fused MLP ----------------
// LDS: A0 [256][128] f16 (64KB). Per-wave 16KB sub-region (rows = wave's 64 nodes):
//   A1[w]: bytes [0,8192)  of sub-region, row stride 128B (wave-private)
//   A2[w]: bytes [8192,12288), row stride 64B (wave-private)
// istd at 65536 (1KB). One barrier total (after cross-wave staging).

__device__ __forceinline__ float swishf(float x) {
    float e = __builtin_amdgcn_exp2f(x * -1.4426950408889634f);
    return x * __builtin_amdgcn_rcpf(1.0f + e);
}

__global__ __launch_bounds__(256, 2)
void scorenet_main(const float* __restrict__ node_attr,
                   const int* __restrict__ gptr, int B,
                   const _Float16* __restrict__ embedh,
                   const float* __restrict__ inv_std_g,
                   const _Float16* __restrict__ w0h,
                   const _Float16* __restrict__ w1h,
                   const _Float16* __restrict__ w2h,
                   const float* __restrict__ b0,
                   const float* __restrict__ b1,
                   const float* __restrict__ b2,
                   float* __restrict__ out) {
    __shared__ __align__(16) char lds[66560];

    const int t    = threadIdx.x;
    const int n0   = blockIdx.x * MT;
    const int lane = t & 63;
    const int wid  = t >> 6;
    const int lr   = lane & 15;
    const int lk   = lane >> 4;

    // ---- early weight/bias fragment loads (L1/L2-resident, hidden under staging) ----
    f16x8 aw0[4][4];                       // [kt][mt] : A row = out-feature mt*16+lr
    #pragma unroll
    for (int kt = 0; kt < 4; ++kt)
        #pragma unroll
        for (int mt = 0; mt < 4; ++mt)
            aw0[kt][mt] = *(const f16x8*)(w0h + (mt * 16 + lr) * 128 + kt * 32 + lk * 8);
    f16x8 aw1[2][2];
    #pragma unroll
    for (int kt = 0; kt < 2; ++kt)
        #pragma unroll
        for (int mt = 0; mt < 2; ++mt)
            aw1[kt][mt] = *(const f16x8*)(w1h + (mt * 16 + lr) * 64 + kt * 32 + lk * 8);
    f16x8 aw2 = *(const f16x8*)(w2h + lr * 32 + lk * 8);
    float4 bias0[4];
    #pragma unroll
    for (int mt = 0; mt < 4; ++mt) bias0[mt] = *(const float4*)(b0 + mt * 16 + lk * 4);
    float4 bias1[2];
    #pragma unroll
    for (int mt = 0; mt < 2; ++mt) bias1[mt] = *(const float4*)(b1 + mt * 16 + lk * 4);
    float4 b2v = *(const float4*)b2;

    // ---- staging: row t = seg lookup + embed copy (rotated); linear node_attr ----
    {
        int node = n0 + t;
        int lo = 0, hi = B + 1;
        while (lo < hi) { int mid = (lo + hi) >> 1; if (gptr[mid] <= node) lo = mid + 1; else hi = mid; }
        int seg = lo - 1;
        ((float*)(lds + ISTD_OFF))[t] = inv_std_g[seg];
        const uint2* src = (const uint2*)(embedh + (size_t)seg * ESTR);
        int rot = t - 21 * (int)(((unsigned)t * 3121u) >> 16);   // t % 21
        const int rswz  = (t & 7) << 4;
        const int rbyte = t * 256;
        #pragma unroll
        for (int m = 0; m < 21; ++m) {
            int mm = m + rot; if (mm >= 21) mm -= 21;
            uint2 v = src[mm];
            int addr = rbyte + 88 + mm * 8;
            *(uint2*)(lds + (addr ^ rswz)) = v;
        }
    }
    {
        const float4* src = (const float4*)(node_attr + (size_t)n0 * FEAT);
        #pragma unroll
        for (int i = 0; i < 11; ++i) {
            int f4   = i * 256 + t;
            int row  = (int)(((unsigned)f4 * 381301u) >> 22);  // f4 / 11
            int colq = f4 - row * 11;
            float4 v = src[f4];
            union { _Float16 h[4]; uint2 u; } cv;
            cv.h[0] = (_Float16)v.x; cv.h[1] = (_Float16)v.y;
            cv.h[2] = (_Float16)v.z; cv.h[3] = (_Float16)v.w;
            int addr = row * 256 + colq * 8;
            *(uint2*)(lds + (addr ^ ((row & 7) << 4))) = cv.u;
        }
    }
    __syncthreads();   // the ONLY barrier

    char* const a0 = lds + wid * 16384;    // wave-private 16KB: rows j=0..63

    // ---- layer 0: D^T[64 out][64 nodes] = W0 x X^T ----
    f32x4 acc0[4][4] = {};                 // [mt][nt]
    #pragma unroll
    for (int kt = 0; kt < 4; ++kt) {
        f16x8 bx[4];
        #pragma unroll
        for (int nt = 0; nt < 4; ++nt) {
            int j    = nt * 16 + lr;
            int addr = j * 256 + kt * 64 + lk * 16;
            bx[nt] = *(const f16x8*)(a0 + (addr ^ ((j & 7) << 4)));
        }
        #pragma unroll
        for (int mt = 0; mt < 4; ++mt)
            #pragma unroll
            for (int nt = 0; nt < 4; ++nt)
                acc0[mt][nt] = __builtin_amdgcn_mfma_f32_16x16x32_f16(aw0[kt][mt], bx[nt], acc0[mt][nt], 0, 0, 0);
    }
    // epilogue 0 -> A1[w] (wave-private, same-wave DS in-order: no barrier)
    #pragma unroll
    for (int mt = 0; mt < 4; ++mt)
        #pragma unroll
        for (int nt = 0; nt < 4; ++nt) {
            int j = nt * 16 + lr;
            float s0 = swishf(acc0[mt][nt][0] + bias0[mt].x);
            float s1 = swishf(acc0[mt][nt][1] + bias0[mt].y);
            float s2 = swishf(acc0[mt][nt][2] + bias0[mt].z);
            float s3 = swishf(acc0[mt][nt][3] + bias0[mt].w);
            union { _Float16 h[4]; uint2 u; } p;
            p.h[0] = (_Float16)s0; p.h[1] = (_Float16)s1;
            p.h[2] = (_Float16)s2; p.h[3] = (_Float16)s3;
            int addr = j * 128 + (mt * 16 + lk * 4) * 2;
            *(uint2*)(a0 + (addr ^ ((j & 7) << 4))) = p.u;
        }

    // ---- layer 1: D^T[32 out][64 nodes] ----
    f32x4 acc1[2][4] = {};
    #pragma unroll
    for (int kt = 0; kt < 2; ++kt) {
        f16x8 bx[4];
        #pragma unroll
        for (int nt = 0; nt < 4; ++nt) {
            int j    = nt * 16 + lr;
            int addr = j * 128 + kt * 64 + lk * 16;
            bx[nt] = *(const f16x8*)(a0 + (addr ^ ((j & 7) << 4)));
        }
        #pragma unroll
        for (int mt = 0; mt < 2; ++mt)
            #pragma unroll
            for (int nt = 0; nt < 4; ++nt)
                acc1[mt][nt] = __builtin_amdgcn_mfma_f32_16x16x32_f16(aw1[kt][mt], bx[nt], acc1[mt][nt], 0, 0, 0);
    }
    // epilogue 1 -> A2[w] at +8192, stride 64B
    #pragma unroll
    for (int mt = 0; mt < 2; ++mt)
        #pragma unroll
        for (int nt = 0; nt < 4; ++nt) {
            int j = nt * 16 + lr;
            float s0 = swishf(acc1[mt][nt][0] + bias1[mt].x);
            float s1 = swishf(acc1[mt][nt][1] + bias1[mt].y);
            float s2 = swishf(acc1[mt][nt][2] + bias1[mt].z);
            float s3 = swishf(acc1[mt][nt][3] + bias1[mt].w);
            union { _Float16 h[4]; uint2 u; } p;
            p.h[0] = (_Float16)s0; p.h[1] = (_Float16)s1;
            p.h[2] = (_Float16)s2; p.h[3] = (_Float16)s3;
            int addr = 8192 + j * 64 + (mt * 16 + lk * 4) * 2;
            *(uint2*)(a0 + (addr ^ ((j & 3) << 4))) = p.u;
        }

    // ---- layer 2: D^T[16(4 valid) out][64 nodes]; direct global store ----
    f32x4 acc2[4] = {};
    #pragma unroll
    for (int nt = 0; nt < 4; ++nt) {
        int j    = nt * 16 + lr;
        int addr = 8192 + j * 64 + lk * 16;
        f16x8 bx = *(const f16x8*)(a0 + (addr ^ ((j & 3) << 4)));
        acc2[nt] = __builtin_amdgcn_mfma_f32_16x16x32_f16(aw2, bx, acc2[nt], 0, 0, 0);
    }
    if (lk == 0) {   // rows 0..3 of D = the 4 valid outputs, all in these lanes
        const float* istd = (const float*)(lds + ISTD_OFF);
        #pragma unroll
        for (int nt = 0; nt < 4; ++nt) {
            int j = nt * 16 + lr;
            float is = istd[wid * 64 + j];
            float4 o;
            o.x = swishf(acc2[nt][0] + b2v.x) * is;
            o.y = swishf(acc2[nt][1] + b2v.y) * is;
            o.z = swishf(acc2[nt][2] + b2v.z) * is;
            o.w = swishf(acc2[nt][3] + b2v.w) * is;
            *(float4*)(out + (size_t)(n0 + wid * 64 + j) * 4) = o;
        }
    }
}

// ---------------- launch ----------------
extern "C" void kernel_launch(void* const* d_in, const int* in_sizes, int n_in,
                              void* d_out, int out_size, void* d_ws, size_t ws_size,
                              hipStream_t stream) {
    const float* node_attr = (const float*)d_in[0];
    const float* t_arr     = (const float*)d_in[1];
    const int*   gptr      = (const int*)d_in[2];
    const float* W_f       = (const float*)d_in[3];
    const float* embed_w   = (const float*)d_in[4];
    const float* embed_b   = (const float*)d_in[5];
    const float* w0        = (const float*)d_in[6];
    const float* b0        = (const float*)d_in[7];
    const float* w1        = (const float*)d_in[8];
    const float* b1        = (const float*)d_in[9];
    const float* w2        = (const float*)d_in[10];
    const float* b2        = (const float*)d_in[11];
    float* out = (float*)d_out;

    const int N = in_sizes[0] / FEAT;
    const int B = in_sizes[1];

    char* ws = (char*)d_ws;
    size_t off = 0;
    _Float16* embedh = (_Float16*)(ws + off); off += (size_t)B * ESTR * sizeof(_Float16);
    off = (off + 1023) & ~(size_t)1023;
    float*    inv_std = (float*)(ws + off);   off += (size_t)B * sizeof(float);
    off = (off + 1023) & ~(size_t)1023;
    _Float16* w0h = (_Float16*)(ws + off);    off += 64 * 128 * sizeof(_Float16);
    _Float16* w1h = (_Float16*)(ws + off);    off += 32 * 64 * sizeof(_Float16);
    _Float16* w2h = (_Float16*)(ws + off);    off += 16 * 32 * sizeof(_Float16);

    prep_weights<<<1, 256, 0, stream>>>(w0, w1, w2, w0h, w1h, w2h);
    embed_kernel<<<B, 128, 0, stream>>>(t_arr, W_f, embed_w, embed_b, embedh, inv_std);
    scorenet_main<<<N / MT, 256, 0, stream>>>(node_attr, gptr, B, embedh, inv_std,
                                              w0h, w1h, w2h, b0, b1, b2, out);
}